// Round 4
// baseline (547.802 us; speedup 1.0000x reference)
//
#include <hip/hip_runtime.h>

#define SEQ 128
#define DIM 1024
#define TOPK 51
#define DECAY 0.99f
#define INHIB 1.5f

typedef float v4f __attribute__((ext_vector_type(4)));

// ---------------- Kernel A: per-row sparsify (relu + top-k threshold) --------
// One block (256 threads) per row. Exact k-th-largest via 4-pass 8-bit radix
// select on the float bit pattern (monotonic for non-negative floats).
// Bin selection: wave-level __shfl_down suffix-scan (no barriers) + one
// cross-wave LDS combine -> 3 barriers/pass. (Unchanged from the 540 µs R4.)
__global__ __launch_bounds__(256) void sparsify_kernel(
    const float* __restrict__ emb, float* __restrict__ s_out,
    int* __restrict__ nnz_idx, int* __restrict__ nnz_cnt)
{
    const int t    = blockIdx.x;
    const int tid  = threadIdx.x;
    const int lane = tid & 63;
    const int wave = tid >> 6;
    const float* x = emb + t * DIM;

    float    v[4];
    unsigned u[4];
#pragma unroll
    for (int e = 0; e < 4; ++e) {
        float val = fmaxf(x[e * 256 + tid], 0.0f);   // relu
        v[e] = val;
        u[e] = __float_as_uint(val);
    }

    __shared__ unsigned hist[256];
    __shared__ unsigned wtot[4];
    __shared__ unsigned sh_prefix;
    __shared__ unsigned sh_k;
    __shared__ int      sh_cnt;
    if (tid == 0) { sh_prefix = 0u; sh_k = TOPK; sh_cnt = 0; }
    hist[tid] = 0u;
    __syncthreads();

    for (int pass = 0; pass < 4; ++pass) {
        const int shift = 24 - 8 * pass;
        const unsigned prefix = sh_prefix;
        const unsigned k      = sh_k;
#pragma unroll
        for (int e = 0; e < 4; ++e) {
            bool ok;
            if (pass == 0) ok = true;
            else           ok = ((u[e] >> (shift + 8)) == (prefix >> (shift + 8)));
            if (ok) atomicAdd(&hist[(u[e] >> shift) & 255u], 1u);
        }
        __syncthreads();

        // Wave-local inclusive suffix-sum over 64 bins (lane i: sum bins i..63)
        unsigned val = hist[tid];
#pragma unroll
        for (int off = 1; off < 64; off <<= 1) {
            unsigned tmp = __shfl_down(val, off, 64);
            if (lane + off < 64) val += tmp;
        }
        if (lane == 0) wtot[wave] = val;
        __syncthreads();

        unsigned addHigher = 0u;
        for (int w = wave + 1; w < 4; ++w) addHigher += wtot[w];
        const unsigned scanFull = val + addHigher;          // suffix over all 256
        const unsigned nxtWithin = __shfl_down(scanFull, 1, 64);
        const unsigned nxt = (lane == 63) ? addHigher : nxtWithin;
        if (scanFull >= k && nxt < k) {
            sh_prefix = prefix | ((unsigned)tid << shift);
            sh_k      = k - nxt;
        }
        hist[tid] = 0u;
        __syncthreads();
    }

    const float thr = __uint_as_float(sh_prefix);
#pragma unroll
    for (int e = 0; e < 4; ++e) {
        const int idx = e * 256 + tid;
        const float sval = (v[e] >= thr) ? v[e] : 0.0f;
        s_out[t * DIM + idx] = sval;
        if (sval > 0.0f) {
            int pos = atomicAdd(&sh_cnt, 1);
            nnz_idx[t * DIM + pos] = idx;
        }
    }
    __syncthreads();
    if (tid == 0) nnz_cnt[t] = sh_cnt;
}

// ---------------- Kernel B: element-parallel state evolution -----------------
// state_t[i,j] = relu(DECAY*state_{t-1}[i,j] + f_t * s_t[i] * s_t[j])
// R7 (plain-HIP decoupling; R5/R6's global_load_lds path killed the container
// twice — abandoned): the store stream is decoupled from the load stream by
//   (a) staging si columns (pre-scaled by f) + fall into LDS once in the
//       prologue -> inner loop reads them via ds_read (lgkmcnt counter,
//       independent of vmcnt), and
//   (b) issuing sj loads in groups of 8 to registers ahead of each
//       8-iteration compute+store block, so a load-use only drains stores
//       that are >= 1 full group (16 stores) old, instead of the ~2-4
//       outstanding stores the per-iteration load pattern allowed.
// Stores remain non-temporal (snapshots are written once, read sparsely).
// LDS ~1.6 KB, VGPR ~60: occupancy unchanged (2 blocks/CU, 8 waves/CU).
__global__ __launch_bounds__(256) void evolve_kernel(
    const float* __restrict__ s, const float* __restrict__ con,
    float* __restrict__ states)
{
    const int i0  = blockIdx.x * 2;
    const int tid = threadIdx.x;

    __shared__ float sic0[SEQ];   // s[t][i0]   * f_t
    __shared__ float sic1[SEQ];   // s[t][i0+1] * f_t

    if (tid < SEQ) {
        const float f = 1.0f - INHIB * con[tid];
        sic0[tid] = s[tid * DIM + i0]     * f;
        sic1[tid] = s[tid * DIM + i0 + 1] * f;
    }
    __syncthreads();

    const float4* s4 = (const float4*)s;   // s4[t*256 + tid] = s[t][tid*4..]

    float st0[4] = {0.f, 0.f, 0.f, 0.f};
    float st1[4] = {0.f, 0.f, 0.f, 0.f};

    for (int c = 0; c < SEQ / 8; ++c) {
        // issue the whole group's sj loads before any of its compute/stores
        float4 pj[8];
#pragma unroll
        for (int r = 0; r < 8; ++r)
            pj[r] = s4[(c * 8 + r) * 256 + tid];

#pragma unroll
        for (int r = 0; r < 8; ++r) {
            const int t = c * 8 + r;
            const float4 sj  = pj[r];
            const float  si0 = sic0[t];
            const float  si1 = sic1[t];

            float* outp = states + (size_t)t * (DIM * DIM)
                                 + (size_t)i0 * DIM + tid * 4;
            v4f o0, o1;
            o0[0] = fmaxf(0.0f, DECAY * st0[0] + si0 * sj.x);
            o0[1] = fmaxf(0.0f, DECAY * st0[1] + si0 * sj.y);
            o0[2] = fmaxf(0.0f, DECAY * st0[2] + si0 * sj.z);
            o0[3] = fmaxf(0.0f, DECAY * st0[3] + si0 * sj.w);
            o1[0] = fmaxf(0.0f, DECAY * st1[0] + si1 * sj.x);
            o1[1] = fmaxf(0.0f, DECAY * st1[1] + si1 * sj.y);
            o1[2] = fmaxf(0.0f, DECAY * st1[2] + si1 * sj.z);
            o1[3] = fmaxf(0.0f, DECAY * st1[3] + si1 * sj.w);
            st0[0] = o0[0]; st0[1] = o0[1]; st0[2] = o0[2]; st0[3] = o0[3];
            st1[0] = o1[0]; st1[1] = o1[1]; st1[2] = o1[2]; st1[3] = o1[3];
            __builtin_nontemporal_store(o0, (v4f*)outp);
            __builtin_nontemporal_store(o1, (v4f*)(outp + DIM));
        }
    }
}

// ---------------- Kernel C: sparse drift ------------------------------------
// drift_t = || s_t - s_t @ state_{t-1} ||_2 ; only ~TOPK rows of state matter.
// One block (256 threads) per t; thread owns 4 consecutive j (float4 loads).
// Unroll 8 keeps 8 HBM row-loads in flight per thread. (Unchanged from R4.)
__global__ __launch_bounds__(256) void drift_kernel(
    const float* __restrict__ s, const int* __restrict__ nnz_idx,
    const int* __restrict__ nnz_cnt, const float* __restrict__ states,
    float* __restrict__ drift)
{
    const int t   = blockIdx.x;
    const int tid = threadIdx.x;
    const int j0  = tid * 4;

    __shared__ int   sh_ix[DIM];
    __shared__ float sh_sv[DIM];

    float e0 = 0.f, e1 = 0.f, e2 = 0.f, e3 = 0.f;
    if (t > 0) {                       // t is block-uniform: no divergent sync
        const int cnt = nnz_cnt[t];
        for (int n = tid; n < cnt; n += 256) {
            const int i = nnz_idx[t * DIM + n];
            sh_ix[n] = i;
            sh_sv[n] = s[t * DIM + i];
        }
        __syncthreads();

        const float* prev = states + (size_t)(t - 1) * DIM * DIM;
        int n = 0;
        for (; n + 8 <= cnt; n += 8) {
            float4 r[8];
            float  a[8];
#pragma unroll
            for (int q = 0; q < 8; ++q) {
                const int i = sh_ix[n + q];
                a[q] = sh_sv[n + q];
                r[q] = *(const float4*)(prev + (size_t)i * DIM + j0);
            }
#pragma unroll
            for (int q = 0; q < 8; ++q) {
                e0 += a[q] * r[q].x;
                e1 += a[q] * r[q].y;
                e2 += a[q] * r[q].z;
                e3 += a[q] * r[q].w;
            }
        }
        for (; n + 4 <= cnt; n += 4) {
            const int ia = sh_ix[n],     ib = sh_ix[n + 1];
            const int ic = sh_ix[n + 2], id = sh_ix[n + 3];
            const float aa = sh_sv[n],     ab = sh_sv[n + 1];
            const float ac = sh_sv[n + 2], ad = sh_sv[n + 3];
            const float4 ra = *(const float4*)(prev + (size_t)ia * DIM + j0);
            const float4 rb = *(const float4*)(prev + (size_t)ib * DIM + j0);
            const float4 rc = *(const float4*)(prev + (size_t)ic * DIM + j0);
            const float4 rd = *(const float4*)(prev + (size_t)id * DIM + j0);
            e0 += aa * ra.x + ab * rb.x + ac * rc.x + ad * rd.x;
            e1 += aa * ra.y + ab * rb.y + ac * rc.y + ad * rd.y;
            e2 += aa * ra.z + ab * rb.z + ac * rc.z + ad * rd.z;
            e3 += aa * ra.w + ab * rb.w + ac * rc.w + ad * rd.w;
        }
        for (; n < cnt; ++n) {
            const int i = sh_ix[n];
            const float si = sh_sv[n];
            const float4 r = *(const float4*)(prev + (size_t)i * DIM + j0);
            e0 += si * r.x; e1 += si * r.y; e2 += si * r.z; e3 += si * r.w;
        }
    }
    const float4 sj = *(const float4*)(s + t * DIM + j0);
    const float d0 = sj.x - e0, d1 = sj.y - e1, d2 = sj.z - e2, d3 = sj.w - e3;
    float local = d0 * d0 + d1 * d1 + d2 * d2 + d3 * d3;

#pragma unroll
    for (int off = 32; off > 0; off >>= 1)
        local += __shfl_down(local, off, 64);

    __shared__ float wsum[4];
    if ((tid & 63) == 0) wsum[tid >> 6] = local;
    __syncthreads();
    if (tid == 0) drift[t] = sqrtf(wsum[0] + wsum[1] + wsum[2] + wsum[3]);
}

extern "C" void kernel_launch(void* const* d_in, const int* in_sizes, int n_in,
                              void* d_out, int out_size, void* d_ws, size_t ws_size,
                              hipStream_t stream)
{
    const float* emb = (const float*)d_in[0];     // [S, D] fp32
    const float* con = (const float*)d_in[1];     // [S]    fp32

    float* drift  = (float*)d_out;                // [S]
    float* states = (float*)d_out + SEQ;          // [S, D, D]

    float* s_buf   = (float*)d_ws;                                   // S*D floats
    int*   nnz_idx = (int*)((char*)d_ws + (size_t)SEQ * DIM * 4);    // S*D ints
    int*   nnz_cnt = (int*)((char*)d_ws + (size_t)2 * SEQ * DIM * 4);// S ints

    sparsify_kernel<<<SEQ, 256, 0, stream>>>(emb, s_buf, nnz_idx, nnz_cnt);
    evolve_kernel<<<DIM / 2, 256, 0, stream>>>(s_buf, con, states);
    drift_kernel<<<SEQ, 256, 0, stream>>>(s_buf, nnz_idx, nnz_cnt, states, drift);
}